// Round 1
// baseline (219.152 us; speedup 1.0000x reference)
//
#include <hip/hip_runtime.h>
#include <hip/hip_bf16.h>
#include <cstdint>
#include <cstddef>

// Problem constants
#define NB 64
#define NK 49
#define NT 512
#define NH 512
#define NA 49

__device__ __forceinline__ float fast_exp(float x) {           // e^x
    return __builtin_amdgcn_exp2f(x * 1.4426950408889634f);
}
__device__ __forceinline__ float fast_tanh(float x) {           // 1 - 2/(e^{2x}+1)
    float e = __builtin_amdgcn_exp2f(x * 2.8853900817779268f);  // e^{2x}
    return 1.0f - 2.0f * __builtin_amdgcn_rcpf(e + 1.0f);
}

// ---------------------------------------------------------------------------
// Prep: transpose the three A x H weight matrices into WT[3][512][64]
// so the GEMV kernel's W reads are wave-uniform contiguous (s_load-able).
// ---------------------------------------------------------------------------
__global__ void kprep(const float* __restrict__ Wg, const float* __restrict__ Ws,
                      const float* __restrict__ Wv, float* __restrict__ WT) {
    const float* src = (blockIdx.x == 0) ? Wg : (blockIdx.x == 1 ? Ws : Wv);
    float* dst = WT + (size_t)blockIdx.x * (NH * 64);
    for (int idx = threadIdx.x; idx < NA * NH; idx += blockDim.x) {
        int a = idx / NH, h = idx - a * NH;
        dst[h * 64 + a] = src[idx];
    }
}

// ---------------------------------------------------------------------------
// GEMV: out[row][a] = sum_h in[row][h] * W[a][h]   for three jobs:
//   rows      0..32767 : h_t x Wg -> gh
//   rows  32768..65535 : s_t x Ws -> ss
//   rows  65536..68671 : V   x Wv -> cv
// Block = 256 threads = 4 waves. lane = row (64 rows/block), wave w handles
// the K-quarter h in [128w, 128w+128). W reads are wave-uniform -> s_loads.
// Partial sums reduced through LDS.
// ---------------------------------------------------------------------------
__global__ __launch_bounds__(256, 3) void kgemv(
        const float* __restrict__ h_t, const float* __restrict__ s_t,
        const float* __restrict__ V, const float* __restrict__ WT,
        float* __restrict__ gh, float* __restrict__ ss, float* __restrict__ cv) {
    __shared__ float part[4 * 64 * NA];

    const int tid  = threadIdx.x;
    const int lane = tid & 63;
    const int w    = __builtin_amdgcn_readfirstlane(tid >> 6);
    const int bid  = blockIdx.x;

    const float* inbase; const float* wt; float* outp; int lrow0;
    if (bid < 512)       { inbase = h_t; wt = WT;               outp = gh; lrow0 = bid * 64; }
    else if (bid < 1024) { inbase = s_t; wt = WT + 1 * NH * 64; outp = ss; lrow0 = (bid - 512)  * 64; }
    else                 { inbase = V;   wt = WT + 2 * NH * 64; outp = cv; lrow0 = (bid - 1024) * 64; }

    const float4* inrow = (const float4*)(inbase + (size_t)(lrow0 + lane) * NH);

    float acc[NA];
    #pragma unroll
    for (int a = 0; a < NA; ++a) acc[a] = 0.0f;

    const float* wtw = wt + w * (128 * 64);   // rows h = 128w .. 128w+127, stride 64
    #pragma unroll 2
    for (int i = 0; i < 32; ++i) {
        float4 v = inrow[w * 32 + i];
        const float* wr = wtw + i * 256;      // 4 consecutive h-rows
        #pragma unroll
        for (int a = 0; a < NA; ++a) {
            acc[a] = fmaf(v.x, wr[a],       acc[a]);
            acc[a] = fmaf(v.y, wr[64 + a],  acc[a]);
            acc[a] = fmaf(v.z, wr[128 + a], acc[a]);
            acc[a] = fmaf(v.w, wr[192 + a], acc[a]);
        }
    }

    float* pp = part + (w * 64 + lane) * NA;
    #pragma unroll
    for (int a = 0; a < NA; ++a) pp[a] = acc[a];
    __syncthreads();

    for (int o = tid; o < 64 * NA; o += 256) {
        float s = part[o] + part[64 * NA + o] + part[2 * 64 * NA + o] + part[3 * 64 * NA + o];
        outp[(size_t)lrow0 * NA + o] = s;
    }
}

// ---------------------------------------------------------------------------
// Main fused kernel: one block per (b, 32-row t-tile). 256 threads.
// phase1: z[t][kk] (kk<49: tanh(cv+gh)·wh ; kk==49: tanh(ss+gh)·wh)
// softmax: alpha (over 49) -> alT[k][t], beta (sentinel of 50-softmax)
// phase3: c_t = alpha^T V (V staged fp32 in LDS, 256-col halves),
//         c_hat = beta*s_t + (1-beta)*c_t
// ---------------------------------------------------------------------------
__global__ __launch_bounds__(256, 2) void kmain(
        const float* __restrict__ V, const float* __restrict__ s_t,
        const float* __restrict__ Wh,
        const float* __restrict__ gh_ws, const float* __restrict__ ss_ws,
        const float* __restrict__ cv_ws,
        float* __restrict__ out_chat, float* __restrict__ out_alpha,
        float* __restrict__ out_beta) {
    __shared__ float Vl[NK * 256];       // 50,176 B (one 256-col half of V[b], fp32)
    __shared__ float cvl[NK * 52];       // 10,192 B ; alT[49][36] overlays after phase 1
    __shared__ float ghl[32 * 52];       //  6,656 B
    __shared__ float ssl[32 * 52];       //  6,656 B
    __shared__ float zl[32 * 50];        //  6,400 B
    __shared__ float betal[32];          //    128 B
    float* alT = cvl;                    // [49][36], stride 36 (16B-aligned rows)

    const int tid = threadIdx.x;
    const int b   = blockIdx.x >> 4;
    const int t0  = (blockIdx.x & 15) * 32;

    // ---- stage cv, gh, ss, V half0
    {
        const float* cvb = cv_ws + (size_t)b * (NK * NA);
        for (int idx = tid; idx < NK * NA; idx += 256) {
            int k = idx / NA, a = idx - k * NA;
            cvl[k * 52 + a] = cvb[idx];
        }
        const float* ghb = gh_ws + ((size_t)b * NT + t0) * NA;
        const float* ssb = ss_ws + ((size_t)b * NT + t0) * NA;
        for (int idx = tid; idx < 32 * NA; idx += 256) {
            int t = idx / NA, a = idx - t * NA;
            ghl[t * 52 + a] = ghb[idx];
            ssl[t * 52 + a] = ssb[idx];
        }
        const float4* Vb = (const float4*)(V + (size_t)b * (NK * NH));
        for (int idx = tid; idx < NK * 64; idx += 256) {
            int k = idx >> 6, q = idx & 63;
            float4 v = Vb[k * 128 + q];
            *(float4*)&Vl[k * 256 + q * 4] = v;
        }
    }
    __syncthreads();

    // ---- phase 1: z
    for (int p = tid; p < 32 * 50; p += 256) {
        int t = p / 50, kk = p - t * 50;
        const float* rowp = (kk < NK) ? (cvl + kk * 52) : (ssl + t * 52);
        const float* gp = ghl + t * 52;
        float z = 0.0f;
        #pragma unroll
        for (int q = 0; q < 12; ++q) {
            float4 r = *(const float4*)(rowp + q * 4);
            float4 g = *(const float4*)(gp + q * 4);
            z = fmaf(Wh[q * 4 + 0], fast_tanh(r.x + g.x), z);
            z = fmaf(Wh[q * 4 + 1], fast_tanh(r.y + g.y), z);
            z = fmaf(Wh[q * 4 + 2], fast_tanh(r.z + g.z), z);
            z = fmaf(Wh[q * 4 + 3], fast_tanh(r.w + g.w), z);
        }
        z = fmaf(Wh[48], fast_tanh(rowp[48] + gp[48]), z);
        zl[p] = z;
    }
    __syncthreads();

    // ---- softmax per t (lanes 0..31 of wave 0)
    if (tid < 32) {
        const float* zr = zl + tid * 50;
        float m49 = -1e30f;
        #pragma unroll
        for (int k = 0; k < NK; ++k) m49 = fmaxf(m49, zr[k]);
        float S = 0.0f;
        #pragma unroll
        for (int k = 0; k < NK; ++k) S += fast_exp(zr[k] - m49);
        float rS = __builtin_amdgcn_rcpf(S);
        #pragma unroll
        for (int k = 0; k < NK; ++k) alT[k * 36 + tid] = fast_exp(zr[k] - m49) * rS;

        float ze   = zr[49];
        float m50  = fmaxf(m49, ze);
        float eext = fast_exp(ze - m50);
        float beta = eext * __builtin_amdgcn_rcpf(S * fast_exp(m49 - m50) + eext);
        betal[tid] = beta;
        out_beta[(size_t)b * NT + t0 + tid] = beta;
    }
    __syncthreads();

    // ---- alpha global write (contiguous)
    {
        float* oa = out_alpha + ((size_t)b * NT + t0) * NK;
        for (int idx = tid; idx < 32 * NK; idx += 256) {
            int t = idx / NK, k = idx - t * NK;
            oa[idx] = alT[k * 36 + t];
        }
    }

    // ---- phase 3: c_t and c_hat, 256-column halves
    #pragma unroll 1
    for (int half = 0; half < 2; ++half) {
        if (half == 1) {
            __syncthreads();   // everyone done with Vl half0
            const float4* Vb = (const float4*)(V + (size_t)b * (NK * NH));
            for (int idx = tid; idx < NK * 64; idx += 256) {
                int k = idx >> 6, q = idx & 63;
                float4 v = Vb[k * 128 + 64 + q];
                *(float4*)&Vl[k * 256 + q * 4] = v;
            }
            __syncthreads();
        }
        float acc[32];
        #pragma unroll
        for (int t = 0; t < 32; ++t) acc[t] = 0.0f;
        for (int k = 0; k < NK; ++k) {
            float v = Vl[k * 256 + tid];
            #pragma unroll
            for (int jj = 0; jj < 8; ++jj) {
                float4 a4 = *(const float4*)&alT[k * 36 + jj * 4];
                acc[jj * 4 + 0] = fmaf(a4.x, v, acc[jj * 4 + 0]);
                acc[jj * 4 + 1] = fmaf(a4.y, v, acc[jj * 4 + 1]);
                acc[jj * 4 + 2] = fmaf(a4.z, v, acc[jj * 4 + 2]);
                acc[jj * 4 + 3] = fmaf(a4.w, v, acc[jj * 4 + 3]);
            }
        }
        const size_t hcol = (size_t)half * 256 + tid;
        const size_t rowbase = (size_t)b * NT + t0;
        #pragma unroll 4
        for (int t = 0; t < 32; ++t) {
            float bt = betal[t];
            size_t off = (rowbase + t) * NH + hcol;
            float s = s_t[off];
            out_chat[off] = fmaf(bt, s - acc[t], acc[t]);  // bt*s + (1-bt)*acc
        }
    }
}

// ---------------------------------------------------------------------------
extern "C" void kernel_launch(void* const* d_in, const int* in_sizes, int n_in,
                              void* d_out, int out_size, void* d_ws, size_t ws_size,
                              hipStream_t stream) {
    const float* V   = (const float*)d_in[0];
    const float* h_t = (const float*)d_in[1];
    const float* s_t = (const float*)d_in[2];
    const float* Wv  = (const float*)d_in[3];
    const float* Wg  = (const float*)d_in[4];
    const float* Ws  = (const float*)d_in[5];
    const float* Wh  = (const float*)d_in[6];

    float* out = (float*)d_out;
    float* out_chat  = out;                                   // B*T*H
    float* out_alpha = out + (size_t)NB * NT * NH;            // B*T*K
    float* out_beta  = out_alpha + (size_t)NB * NT * NK;      // B*T

    // workspace layout (floats): WT[3*512*64] | gh[32768*49] | ss[32768*49] | cv[3136*49]
    float* ws  = (float*)d_ws;
    float* WT  = ws;
    float* gh  = WT + 3 * NH * 64;                 // 98,304
    float* ss  = gh + (size_t)NB * NT * NA;        // +1,605,632
    float* cv  = ss + (size_t)NB * NT * NA;        // +1,605,632
    // total 3,463,232 floats = 13.85 MB

    kprep<<<3, 256, 0, stream>>>(Wg, Ws, Wv, WT);
    kgemv<<<1073, 256, 0, stream>>>(h_t, s_t, V, WT, gh, ss, cv);
    kmain<<<NB * (NT / 32), 256, 0, stream>>>(V, s_t, Wh, gh, ss, cv,
                                              out_chat, out_alpha, out_beta);
}

// Round 2
// 203.770 us; speedup vs baseline: 1.0755x; 1.0755x over previous
//
#include <hip/hip_runtime.h>
#include <hip/hip_bf16.h>
#include <cstdint>
#include <cstddef>

// Problem constants
#define NB 64
#define NK 49
#define NT 512
#define NH 512
#define NA 49

typedef __attribute__((ext_vector_type(8))) short bf16x8;
typedef __attribute__((ext_vector_type(4))) float f32x4;

__device__ __forceinline__ float fast_exp(float x) {           // e^x
    return __builtin_amdgcn_exp2f(x * 1.4426950408889634f);
}
__device__ __forceinline__ float fast_tanh(float x) {           // 1 - 2/(e^{2x}+1)
    float e = __builtin_amdgcn_exp2f(x * 2.8853900817779268f);  // e^{2x}
    return 1.0f - 2.0f * __builtin_amdgcn_rcpf(e + 1.0f);
}
__device__ __forceinline__ short bf16rn(float x) {              // round-to-nearest-even bf16
    unsigned b = __builtin_bit_cast(unsigned, x);
    unsigned r = b + 0x7FFFu + ((b >> 16) & 1u);
    return (short)(r >> 16);
}

// ---------------------------------------------------------------------------
// Prep: swizzle the three A x H weight matrices into MFMA B-fragment order.
// Layout (bf16): WB[job][sel(hi/lo)][ntile(4)][kstep(16)][lane(64)][e(8)]
//   B[k][n]: n = ntile*16 + (lane&15), k = kstep*32 + (lane>>4)*8 + e
// a >= 49 columns are zero-padded. 65536 bf16 (128 KB) per job.
// ---------------------------------------------------------------------------
__global__ void kprep(const float* __restrict__ Wg, const float* __restrict__ Ws,
                      const float* __restrict__ Wv, short* __restrict__ WB) {
    const float* W = (blockIdx.x == 0) ? Wg : (blockIdx.x == 1 ? Ws : Wv);
    short* dst = WB + (size_t)blockIdx.x * 65536;
    for (int idx = threadIdx.x; idx < 65536; idx += blockDim.x) {
        int e    = idx & 7;
        int lane = (idx >> 3) & 63;
        int ks   = (idx >> 9) & 15;
        int nt   = (idx >> 13) & 3;
        int sel  = idx >> 15;
        int a = nt * 16 + (lane & 15);
        int h = ks * 32 + (lane >> 4) * 8 + e;
        float x = (a < NA) ? W[a * NH + h] : 0.0f;
        unsigned b = __builtin_bit_cast(unsigned, x);
        short v;
        if (sel == 0) {
            v = (short)(b >> 16);                           // truncated hi
        } else {
            float hf = __builtin_bit_cast(float, b & 0xFFFF0000u);
            v = bf16rn(x - hf);                             // rounded residual
        }
        dst[idx] = v;
    }
}

// ---------------------------------------------------------------------------
// GEMM via MFMA: out[row][a] = sum_h in[row][h] * W[a][h], fp32 in/out,
// bf16 hi/lo split (hi*hi + lo*hi + hi*lo -> ~2^-17 relative error).
//   blocks    0..511 : h_t x Wg -> gh
//   blocks 512..1023 : s_t x Ws -> ss
//   blocks 1024..1072: V   x Wv -> cv
// Block = 4 waves; wave w owns 16 rows (m0 = row0 + 16w), all 64 (padded)
// output cols as 4 N-tiles. K = 512 = 16 steps of 32. No LDS.
// ---------------------------------------------------------------------------
__global__ __launch_bounds__(256, 4) void kgemm(
        const float* __restrict__ h_t, const float* __restrict__ s_t,
        const float* __restrict__ V, const short* __restrict__ WB,
        float* __restrict__ gh, float* __restrict__ ss, float* __restrict__ cv) {
    const int tid  = threadIdx.x;
    const int lane = tid & 63;
    const int w    = tid >> 6;
    const int bid  = blockIdx.x;

    const float* in; const short* wb; float* outp; int row0;
    if (bid < 512)       { in = h_t; wb = WB;           outp = gh; row0 = bid * 64; }
    else if (bid < 1024) { in = s_t; wb = WB + 65536;   outp = ss; row0 = (bid - 512)  * 64; }
    else                 { in = V;   wb = WB + 131072;  outp = cv; row0 = (bid - 1024) * 64; }

    const int m0 = row0 + w * 16;
    const int r  = lane & 15;         // A row / B col / D col within tile
    const int g  = lane >> 4;         // k-group
    const float* arow = in + (size_t)(m0 + r) * NH + g * 8;
    const bf16x8* wbv = (const bf16x8*)wb;

    f32x4 acc0 = {0.f, 0.f, 0.f, 0.f};
    f32x4 acc1 = acc0, acc2 = acc0, acc3 = acc0;

    #pragma unroll 2
    for (int ks = 0; ks < 16; ++ks) {
        float4 x0 = *(const float4*)(arow + ks * 32);
        float4 x1 = *(const float4*)(arow + ks * 32 + 4);
        bf16x8 bh0 = wbv[(0 * 16 + ks) * 64 + lane];
        bf16x8 bh1 = wbv[(1 * 16 + ks) * 64 + lane];
        bf16x8 bh2 = wbv[(2 * 16 + ks) * 64 + lane];
        bf16x8 bh3 = wbv[(3 * 16 + ks) * 64 + lane];
        bf16x8 bl0 = wbv[(4 * 16 + ks) * 64 + lane];
        bf16x8 bl1 = wbv[(5 * 16 + ks) * 64 + lane];
        bf16x8 bl2 = wbv[(6 * 16 + ks) * 64 + lane];
        bf16x8 bl3 = wbv[(7 * 16 + ks) * 64 + lane];

        bf16x8 ahi, alo;
        {
            const float xs[8] = {x0.x, x0.y, x0.z, x0.w, x1.x, x1.y, x1.z, x1.w};
            #pragma unroll
            for (int e = 0; e < 8; ++e) {
                unsigned b = __builtin_bit_cast(unsigned, xs[e]);
                unsigned hb = b & 0xFFFF0000u;
                ahi[e] = (short)(hb >> 16);
                alo[e] = bf16rn(xs[e] - __builtin_bit_cast(float, hb));
            }
        }
        acc0 = __builtin_amdgcn_mfma_f32_16x16x32_bf16(ahi, bh0, acc0, 0, 0, 0);
        acc0 = __builtin_amdgcn_mfma_f32_16x16x32_bf16(alo, bh0, acc0, 0, 0, 0);
        acc0 = __builtin_amdgcn_mfma_f32_16x16x32_bf16(ahi, bl0, acc0, 0, 0, 0);
        acc1 = __builtin_amdgcn_mfma_f32_16x16x32_bf16(ahi, bh1, acc1, 0, 0, 0);
        acc1 = __builtin_amdgcn_mfma_f32_16x16x32_bf16(alo, bh1, acc1, 0, 0, 0);
        acc1 = __builtin_amdgcn_mfma_f32_16x16x32_bf16(ahi, bl1, acc1, 0, 0, 0);
        acc2 = __builtin_amdgcn_mfma_f32_16x16x32_bf16(ahi, bh2, acc2, 0, 0, 0);
        acc2 = __builtin_amdgcn_mfma_f32_16x16x32_bf16(alo, bh2, acc2, 0, 0, 0);
        acc2 = __builtin_amdgcn_mfma_f32_16x16x32_bf16(ahi, bl2, acc2, 0, 0, 0);
        acc3 = __builtin_amdgcn_mfma_f32_16x16x32_bf16(ahi, bh3, acc3, 0, 0, 0);
        acc3 = __builtin_amdgcn_mfma_f32_16x16x32_bf16(alo, bh3, acc3, 0, 0, 0);
        acc3 = __builtin_amdgcn_mfma_f32_16x16x32_bf16(ahi, bl3, acc3, 0, 0, 0);
    }

    // D layout: col = lane&15 (within tile), row = (lane>>4)*4 + reg  [m89]
    #pragma unroll
    for (int reg = 0; reg < 4; ++reg) {
        int row = m0 + g * 4 + reg;
        float* orow = outp + (size_t)row * NA;
        orow[ 0 + r] = acc0[reg];
        orow[16 + r] = acc1[reg];
        orow[32 + r] = acc2[reg];
        if (r == 0) orow[48] = acc3[reg];
    }
}

// ---------------------------------------------------------------------------
// Main fused kernel: one block per (b, 32-row t-tile). 512 threads, 8 waves.
// phase1: z[t][kk] (kk<49: tanh(cv+gh)·wh ; kk==49: tanh(ss+gh)·wh)
// softmax: alpha (over 49) -> alT[k][t] (overlays cvl), beta (sentinel)
// phase3: c_t = alpha^T V with V read straight from global (L2-resident),
//         col = tid; c_hat = beta*s_t + (1-beta)*c_t
// LDS ~30 KB -> 3 blocks/CU at launch_bounds(512,6).
// ---------------------------------------------------------------------------
__global__ __launch_bounds__(512, 6) void kmain(
        const float* __restrict__ V, const float* __restrict__ s_t,
        const float* __restrict__ Wh,
        const float* __restrict__ gh_ws, const float* __restrict__ ss_ws,
        const float* __restrict__ cv_ws,
        float* __restrict__ out_chat, float* __restrict__ out_alpha,
        float* __restrict__ out_beta) {
    __shared__ float cvl[NK * 52];       // 10,192 B ; alT[49][36] overlays after phase 1
    __shared__ float ghl[32 * 52];       //  6,656 B
    __shared__ float ssl[32 * 52];       //  6,656 B
    __shared__ float zl[32 * 50];        //  6,400 B
    __shared__ float betal[32];          //    128 B
    float* alT = cvl;                    // [49][36], stride 36 (16B-aligned rows)

    const int tid = threadIdx.x;
    const int b   = blockIdx.x >> 4;
    const int t0  = (blockIdx.x & 15) * 32;

    // ---- stage cv, gh, ss
    {
        const float* cvb = cv_ws + (size_t)b * (NK * NA);
        for (int idx = tid; idx < NK * NA; idx += 512) {
            int k = idx / NA, a = idx - k * NA;
            cvl[k * 52 + a] = cvb[idx];
        }
        const float* ghb = gh_ws + ((size_t)b * NT + t0) * NA;
        const float* ssb = ss_ws + ((size_t)b * NT + t0) * NA;
        for (int idx = tid; idx < 32 * NA; idx += 512) {
            int t = idx / NA, a = idx - t * NA;
            ghl[t * 52 + a] = ghb[idx];
            ssl[t * 52 + a] = ssb[idx];
        }
    }
    __syncthreads();

    // ---- phase 1: z
    for (int p = tid; p < 32 * 50; p += 512) {
        int t = p / 50, kk = p - t * 50;
        const float* rowp = (kk < NK) ? (cvl + kk * 52) : (ssl + t * 52);
        const float* gp = ghl + t * 52;
        float z = 0.0f;
        #pragma unroll
        for (int q = 0; q < 12; ++q) {
            float4 rr = *(const float4*)(rowp + q * 4);
            float4 gg = *(const float4*)(gp + q * 4);
            z = fmaf(Wh[q * 4 + 0], fast_tanh(rr.x + gg.x), z);
            z = fmaf(Wh[q * 4 + 1], fast_tanh(rr.y + gg.y), z);
            z = fmaf(Wh[q * 4 + 2], fast_tanh(rr.z + gg.z), z);
            z = fmaf(Wh[q * 4 + 3], fast_tanh(rr.w + gg.w), z);
        }
        z = fmaf(Wh[48], fast_tanh(rowp[48] + gp[48]), z);
        zl[p] = z;
    }
    __syncthreads();

    // ---- softmax per t (lanes 0..31 of wave 0); alT overlays cvl (safe: past barrier)
    if (tid < 32) {
        const float* zr = zl + tid * 50;
        float m49 = -1e30f;
        #pragma unroll
        for (int k = 0; k < NK; ++k) m49 = fmaxf(m49, zr[k]);
        float S = 0.0f;
        #pragma unroll
        for (int k = 0; k < NK; ++k) S += fast_exp(zr[k] - m49);
        float rS = __builtin_amdgcn_rcpf(S);
        #pragma unroll
        for (int k = 0; k < NK; ++k) alT[k * 36 + tid] = fast_exp(zr[k] - m49) * rS;

        float ze   = zr[49];
        float m50  = fmaxf(m49, ze);
        float eext = fast_exp(ze - m50);
        float beta = eext * __builtin_amdgcn_rcpf(S * fast_exp(m49 - m50) + eext);
        betal[tid] = beta;
        out_beta[(size_t)b * NT + t0 + tid] = beta;
    }
    __syncthreads();

    // ---- alpha global write (contiguous)
    {
        float* oa = out_alpha + ((size_t)b * NT + t0) * NK;
        for (int idx = tid; idx < 32 * NK; idx += 512) {
            int t = idx / NK, k = idx - t * NK;
            oa[idx] = alT[k * 36 + t];
        }
    }

    // ---- phase 3: c_t (V from global/L2) and c_hat. col = tid.
    {
        float acc[32];
        #pragma unroll
        for (int t = 0; t < 32; ++t) acc[t] = 0.0f;
        const float* Vb = V + (size_t)b * (NK * NH) + tid;
        #pragma unroll 7
        for (int k = 0; k < NK; ++k) {
            float v = Vb[(size_t)k * NH];
            #pragma unroll
            for (int jj = 0; jj < 8; ++jj) {
                float4 a4 = *(const float4*)&alT[k * 36 + jj * 4];  // uniform -> broadcast
                acc[jj * 4 + 0] = fmaf(a4.x, v, acc[jj * 4 + 0]);
                acc[jj * 4 + 1] = fmaf(a4.y, v, acc[jj * 4 + 1]);
                acc[jj * 4 + 2] = fmaf(a4.z, v, acc[jj * 4 + 2]);
                acc[jj * 4 + 3] = fmaf(a4.w, v, acc[jj * 4 + 3]);
            }
        }
        const size_t rowbase = (size_t)b * NT + t0;
        #pragma unroll 4
        for (int t = 0; t < 32; ++t) {
            float bt = betal[t];
            size_t off = (rowbase + t) * NH + tid;
            float s = s_t[off];
            out_chat[off] = fmaf(bt, s - acc[t], acc[t]);  // bt*s + (1-bt)*acc
        }
    }
}

// ---------------------------------------------------------------------------
extern "C" void kernel_launch(void* const* d_in, const int* in_sizes, int n_in,
                              void* d_out, int out_size, void* d_ws, size_t ws_size,
                              hipStream_t stream) {
    const float* V   = (const float*)d_in[0];
    const float* h_t = (const float*)d_in[1];
    const float* s_t = (const float*)d_in[2];
    const float* Wv  = (const float*)d_in[3];
    const float* Wg  = (const float*)d_in[4];
    const float* Ws  = (const float*)d_in[5];
    const float* Wh  = (const float*)d_in[6];

    float* out = (float*)d_out;
    float* out_chat  = out;                                   // B*T*H
    float* out_alpha = out + (size_t)NB * NT * NH;            // B*T*K
    float* out_beta  = out_alpha + (size_t)NB * NT * NK;      // B*T

    // workspace: WB (3*65536 bf16 = 384 KB) | gh | ss | cv   (~13.85 MB total)
    short* WB = (short*)d_ws;
    float* gh = (float*)((char*)d_ws + 3 * 65536 * sizeof(short));
    float* ss = gh + (size_t)NB * NT * NA;
    float* cv = ss + (size_t)NB * NT * NA;

    kprep<<<3, 256, 0, stream>>>(Wg, Ws, Wv, WB);
    kgemm<<<1073, 256, 0, stream>>>(h_t, s_t, V, WB, gh, ss, cv);
    kmain<<<NB * (NT / 32), 512, 0, stream>>>(V, s_t, Wh, gh, ss, cv,
                                              out_chat, out_alpha, out_beta);
}